// Round 1
// baseline (463.315 us; speedup 1.0000x reference)
//
#include <hip/hip_runtime.h>
#include <hip/hip_bf16.h>

// ---------------------------------------------------------------------------
// AdvisorCrossAttention on MI355X (gfx950)
// Pipeline: f32->bf16 converts; bf16 MFMA GEMMs (m97-style 128x128 tile,
// BK=32, global_load_lds width-16); logic-gate V combine (+transpose);
// f32 scores + wave-per-row softmax; PV GEMM; output GEMM -> f32.
// Dims: B=8, S=2048, H=1024, L=1536 (T=512 triples).
// ---------------------------------------------------------------------------

typedef unsigned short u16;
typedef __attribute__((ext_vector_type(8))) short bf16x8;   // 8 bf16 = 4 VGPRs
typedef __attribute__((ext_vector_type(4))) float f32x4;    // MFMA acc
typedef __attribute__((ext_vector_type(4))) unsigned short u16x4;

__device__ __forceinline__ u16 f2bf(float f) {
    __hip_bfloat16 h = __float2bfloat16(f);
    return *reinterpret_cast<u16*>(&h);
}
__device__ __forceinline__ float bf2f(u16 u) {
    __hip_bfloat16 h;
    *reinterpret_cast<u16*>(&h) = u;
    return __bfloat162float(h);
}

__device__ __forceinline__ void gload_lds16(const u16* g, u16* l) {
    __builtin_amdgcn_global_load_lds(
        (const __attribute__((address_space(1))) void*)g,
        (__attribute__((address_space(3))) void*)l, 16, 0, 0);
}

__device__ __forceinline__ void store_c(float* p, float v) { *p = v; }
__device__ __forceinline__ void store_c(u16* p, float v)   { *p = f2bf(v); }

// ---------------------------------------------------------------------------
// GEMM: C[m,n] = alpha * sum_k A[m,k] * B[n,k]     (A: MxK, B: NxK, row-major)
// 128x128 block tile, BK=32, 4 waves (2x2), each wave 64x64 via 4x4 frags of
// 16x16x32 bf16 MFMA. Batched via blockIdx.z with element strides.
// ---------------------------------------------------------------------------
template <typename TC>
__global__ __launch_bounds__(256) void gemm_bt(
    const u16* __restrict__ A, const u16* __restrict__ B, TC* __restrict__ C,
    int K, int lda, int ldb, int ldc,
    long sA, long sB, long sC, float alpha)
{
    __shared__ u16 As[128 * 32];
    __shared__ u16 Bs[128 * 32];

    const int  tid     = threadIdx.x;
    const int  z       = blockIdx.z;
    const long rowBase = (long)blockIdx.y * 128;
    const long colBase = (long)blockIdx.x * 128;

    const u16* Ab = A + z * sA + rowBase * lda;
    const u16* Bb = B + z * sB + colBase * ldb;

    const int l   = tid & 63;
    const int wid = tid >> 6;
    const int wr  = (wid >> 1) * 64;   // wave row offset in tile
    const int wc  = (wid & 1) * 64;    // wave col offset in tile
    const int lr  = l & 15;            // fragment row/col lane index
    const int lk  = (l >> 4) * 8;      // fragment k offset

    // staging: 8KB per tile = 512 x 16B chunks; 256 threads -> 2 rounds each
    const int c0  = tid,        c1  = 256 + tid;
    const int ar0 = c0 >> 2,    ak0 = (c0 & 3) * 8;
    const int ar1 = c1 >> 2,    ak1 = (c1 & 3) * 8;

    f32x4 acc[4][4] = {};

    for (int k0 = 0; k0 < K; k0 += 32) {
        gload_lds16(Ab + (long)ar0 * lda + k0 + ak0, &As[c0 * 8]);
        gload_lds16(Ab + (long)ar1 * lda + k0 + ak1, &As[c1 * 8]);
        gload_lds16(Bb + (long)ar0 * ldb + k0 + ak0, &Bs[c0 * 8]);
        gload_lds16(Bb + (long)ar1 * ldb + k0 + ak1, &Bs[c1 * 8]);
        asm volatile("s_waitcnt vmcnt(0)" ::: "memory");
        __syncthreads();

        bf16x8 af[4], bf[4];
#pragma unroll
        for (int m = 0; m < 4; ++m)
            af[m] = *(const bf16x8*)&As[(wr + m * 16 + lr) * 32 + lk];
#pragma unroll
        for (int n = 0; n < 4; ++n)
            bf[n] = *(const bf16x8*)&Bs[(wc + n * 16 + lr) * 32 + lk];
#pragma unroll
        for (int m = 0; m < 4; ++m)
#pragma unroll
            for (int n = 0; n < 4; ++n)
                acc[m][n] = __builtin_amdgcn_mfma_f32_16x16x32_bf16(
                    af[m], bf[n], acc[m][n], 0, 0, 0);
        __syncthreads();
    }

    // epilogue: D lane mapping col = l&15, row = (l>>4)*4 + j  [guide §3, m89]
    TC*        Cb = C + z * sC;
    const long rB = rowBase + wr + (l >> 4) * 4;
    const long cB = colBase + wc + lr;
#pragma unroll
    for (int m = 0; m < 4; ++m)
#pragma unroll
        for (int n = 0; n < 4; ++n)
#pragma unroll
            for (int j = 0; j < 4; ++j)
                store_c(&Cb[(rB + m * 16 + j) * ldc + cB + n * 16],
                        acc[m][n][j] * alpha);
}

// ---------------------------------------------------------------------------
// f32 -> bf16 convert, 4 elems/thread
// ---------------------------------------------------------------------------
__global__ __launch_bounds__(256) void cvt_f32_bf16(
    const float* __restrict__ in, u16* __restrict__ out, long n)
{
    long i = ((long)blockIdx.x * 256 + threadIdx.x) * 4;
    if (i >= n) return;
    float4 v = *(const float4*)(in + i);
    u16x4 w = { f2bf(v.x), f2bf(v.y), f2bf(v.z), f2bf(v.w) };
    *(u16x4*)(out + i) = w;
}

// ---------------------------------------------------------------------------
// V combine (logic gates on triplet projections) + transpose to Vt[b][o][t]
// grid (T/64, H/64, B), block (16,16). LDS 64x64 tile (+pad).
// vp rows: (b*512+t)*3 + k, 1024 cols.
// ---------------------------------------------------------------------------
__global__ __launch_bounds__(256) void combine_v(
    const u16* __restrict__ vp, const int* __restrict__ ids,
    u16* __restrict__ Vt)
{
    __shared__ u16 tile[64][68];
    const int b  = blockIdx.z;
    const int t0 = blockIdx.x * 64;
    const int o0 = blockIdx.y * 64;
    const int tx = threadIdx.x;   // 0..15 -> o chunks (read), t chunks (write)
    const int ty = threadIdx.y;   // 0..15

#pragma unroll
    for (int i = 0; i < 4; ++i) {
        const int  tloc = ty + i * 16;
        const int  t    = t0 + tloc;
        const long base = ((long)(b * 512 + t) * 3) * 1024 + o0 + tx * 4;
        const int  rel  = ids[(b * 512 + t) * 3];
        u16x4 r0 = *(const u16x4*)(vp + base);           // v_rel (k=0)
        u16x4 r1 = *(const u16x4*)(vp + base + 1024);    // v1    (k=1)
        u16x4 r2 = *(const u16x4*)(vp + base + 2048);    // v2    (k=2)
#pragma unroll
        for (int c = 0; c < 4; ++c) {
            float vr = bf2f(r0[c]);
            float x1 = bf2f(r1[c]);
            float x2 = bf2f(r2[c]);
            float vf;
            switch (rel) {
                case 0:  vf = fminf(x1, x2);        break;  // AND
                case 1:  vf = fmaxf(x1, x2);        break;  // OR
                case 2:  vf = -x1;                  break;  // NOT
                case 3:  vf = fmaxf(-x1, x2);       break;  // IMP
                case 4:  vf = fabsf(x1 - x2);       break;  // XOR
                default: vf = vr;                   break;  // LRN (>=5)
            }
            tile[tloc][tx * 4 + c] = f2bf(vf);
        }
    }
    __syncthreads();
#pragma unroll
    for (int j = 0; j < 4; ++j) {
        const int ol = ty + j * 16;
        u16x4 w;
#pragma unroll
        for (int c = 0; c < 4; ++c) w[c] = tile[tx * 4 + c][ol];
        *(u16x4*)(Vt + ((long)(b * 1024 + o0 + ol)) * 512 + t0 + tx * 4) = w;
    }
}

// ---------------------------------------------------------------------------
// Row softmax over 512 f32 scores -> bf16 probs. One wave per row.
// ---------------------------------------------------------------------------
__global__ __launch_bounds__(256) void softmax_rows(
    const float* __restrict__ S, u16* __restrict__ P)
{
    const int row = blockIdx.x * 4 + (threadIdx.x >> 6);
    const int l   = threadIdx.x & 63;
    const float4* src = (const float4*)(S + (long)row * 512);
    float4 a = src[l];
    float4 b = src[64 + l];

    float m = fmaxf(fmaxf(fmaxf(a.x, a.y), fmaxf(a.z, a.w)),
                    fmaxf(fmaxf(b.x, b.y), fmaxf(b.z, b.w)));
#pragma unroll
    for (int off = 32; off; off >>= 1) m = fmaxf(m, __shfl_xor(m, off));

    a.x = __expf(a.x - m); a.y = __expf(a.y - m);
    a.z = __expf(a.z - m); a.w = __expf(a.w - m);
    b.x = __expf(b.x - m); b.y = __expf(b.y - m);
    b.z = __expf(b.z - m); b.w = __expf(b.w - m);

    float s = a.x + a.y + a.z + a.w + b.x + b.y + b.z + b.w;
#pragma unroll
    for (int off = 32; off; off >>= 1) s += __shfl_xor(s, off);
    const float inv = 1.0f / s;

    u16x4 w0 = { f2bf(a.x * inv), f2bf(a.y * inv), f2bf(a.z * inv), f2bf(a.w * inv) };
    u16x4 w1 = { f2bf(b.x * inv), f2bf(b.y * inv), f2bf(b.z * inv), f2bf(b.w * inv) };
    u16x4* dst = (u16x4*)(P + (long)row * 512);
    dst[l]      = w0;
    dst[64 + l] = w1;
}

// ---------------------------------------------------------------------------
extern "C" void kernel_launch(void* const* d_in, const int* in_sizes, int n_in,
                              void* d_out, int out_size, void* d_ws, size_t ws_size,
                              hipStream_t stream)
{
    const float* hidden  = (const float*)d_in[0];   // 8*2048*1024
    const float* advisor = (const float*)d_in[1];   // 8*1536*1024
    const int*   ids     = (const int*)d_in[2];     // 8*1536
    const float* Wq      = (const float*)d_in[3];
    const float* Wk      = (const float*)d_in[4];
    const float* Wv      = (const float*)d_in[5];
    const float* Wo      = (const float*)d_in[6];
    float*       out     = (float*)d_out;           // 8*2048*1024 f32

    char* ws = (char*)d_ws;
    const long MB = 1L << 20;
    // workspace layout (lifetime-overlapped):
    u16*   Wq_bf  = (u16*)(ws + 0 * MB);     // 2MB
    u16*   Wk_bf  = (u16*)(ws + 2 * MB);     // 2MB
    u16*   Wv_bf  = (u16*)(ws + 4 * MB);     // 2MB
    u16*   Wo_bf  = (u16*)(ws + 6 * MB);     // 2MB
    u16*   Hbf    = (u16*)(ws + 8 * MB);     // 32MB  (dead after Q gemm)
    float* scores = (float*)(ws + 8 * MB);   // 32MB  (reuses Hbf)
    u16*   Abf    = (u16*)(ws + 40 * MB);    // 24MB  (dead after K/V gemms)
    u16*   P      = (u16*)(ws + 40 * MB);    // 16MB  (reuses Abf)
    u16*   Qbf    = (u16*)(ws + 64 * MB);    // 32MB  (dead after scores)
    u16*   ctx    = (u16*)(ws + 64 * MB);    // 32MB  (reuses Qbf)
    u16*   Kf     = (u16*)(ws + 96 * MB);    // 8MB
    u16*   Vt     = (u16*)(ws + 104 * MB);   // 8MB
    u16*   vp     = (u16*)(ws + 112 * MB);   // 24MB   -> peak 136MB

    // 1) converts
    cvt_f32_bf16<<<16384, 256, 0, stream>>>(hidden,  Hbf, 16777216L);
    cvt_f32_bf16<<<12288, 256, 0, stream>>>(advisor, Abf, 12582912L);
    cvt_f32_bf16<<<1024,  256, 0, stream>>>(Wq, Wq_bf, 1048576L);
    cvt_f32_bf16<<<1024,  256, 0, stream>>>(Wk, Wk_bf, 1048576L);
    cvt_f32_bf16<<<1024,  256, 0, stream>>>(Wv, Wv_bf, 1048576L);
    cvt_f32_bf16<<<1024,  256, 0, stream>>>(Wo, Wo_bf, 1048576L);

    // 2) projections
    // Q = hidden @ Wq^T   (16384 x 1024)
    gemm_bt<u16><<<dim3(8, 128, 1), 256, 0, stream>>>(
        Hbf, Wq_bf, Qbf, 1024, 1024, 1024, 1024, 0, 0, 0, 1.0f);
    // K = trip0 @ Wk^T    (4096 x 1024), row stride 3*1024
    gemm_bt<u16><<<dim3(8, 32, 1), 256, 0, stream>>>(
        Abf, Wk_bf, Kf, 1024, 3072, 1024, 1024, 0, 0, 0, 1.0f);
    // Vproj = advisor @ Wv^T (12288 x 1024)
    gemm_bt<u16><<<dim3(8, 96, 1), 256, 0, stream>>>(
        Abf, Wv_bf, vp, 1024, 1024, 1024, 1024, 0, 0, 0, 1.0f);

    // 3) logic-gate combine + transpose -> Vt[b][o][t]
    combine_v<<<dim3(8, 16, 8), dim3(16, 16), 0, stream>>>(vp, ids, Vt);

    // 4) scores = Q @ K^T / 32   (per batch 2048 x 512, K=1024), f32
    gemm_bt<float><<<dim3(4, 16, 8), 256, 0, stream>>>(
        Qbf, Kf, scores, 1024, 1024, 1024, 512,
        2048L * 1024, 512L * 1024, 2048L * 512, 0.03125f);

    // 5) softmax rows -> P bf16
    softmax_rows<<<4096, 256, 0, stream>>>(scores, P);

    // 6) ctx = P @ Vt^T  (per batch 2048 x 1024, K=512)
    gemm_bt<u16><<<dim3(8, 16, 8), 256, 0, stream>>>(
        P, Vt, ctx, 512, 512, 512, 1024,
        2048L * 512, 1024L * 512, 2048L * 1024, 1.0f);

    // 7) out = ctx @ Wo^T  (16384 x 1024) -> f32
    gemm_bt<float><<<dim3(8, 128, 1), 256, 0, stream>>>(
        ctx, Wo_bf, out, 1024, 1024, 1024, 1024, 0, 0, 0, 1.0f);
}

// Round 8
// 361.113 us; speedup vs baseline: 1.2830x; 1.2830x over previous
//
#include <hip/hip_runtime.h>
#include <hip/hip_bf16.h>

// ---------------------------------------------------------------------------
// AdvisorCrossAttention on MI355X (gfx950) — round 7 (resubmit: rounds 1-6
// never ran; GPU acquisition timed out each time)
// GEMMs upgraded to counted-vmcnt double-buffer pipeline (T3/T4-lite):
//   raw s_barrier (no drain), stage t+2 in flight across barriers, vmcnt(8),
//   T2 both-sides LDS XOR swizzle, T1 bijective XCD block swizzle, T5 setprio.
// Tiles: 256x256 (8 waves) for big GEMMs, 128x128 (4 waves) for batched ones.
// ---------------------------------------------------------------------------

typedef unsigned short u16;
typedef __attribute__((ext_vector_type(8))) short bf16x8;   // 8 bf16 = 4 VGPRs
typedef __attribute__((ext_vector_type(4))) float f32x4;    // MFMA acc
typedef __attribute__((ext_vector_type(4))) unsigned short u16x4;

__device__ __forceinline__ u16 f2bf(float f) {
    __hip_bfloat16 h = __float2bfloat16(f);
    return *reinterpret_cast<u16*>(&h);
}
__device__ __forceinline__ float bf2f(u16 u) {
    __hip_bfloat16 h;
    *reinterpret_cast<u16*>(&h) = u;
    return __bfloat162float(h);
}

__device__ __forceinline__ void gload_lds16(const u16* g, u16* l) {
    __builtin_amdgcn_global_load_lds(
        (const __attribute__((address_space(1))) void*)g,
        (__attribute__((address_space(3))) void*)l, 16, 0, 0);
}

__device__ __forceinline__ void store_c(float* p, float v) { *p = v; }
__device__ __forceinline__ void store_c(u16* p, float v)   { *p = f2bf(v); }

// ---------------------------------------------------------------------------
// Pipelined GEMM: C[m,n] = alpha * sum_k A[m,k]*B[n,k]  (A: MxK, B: NxK)
// BK = 64. Double-buffered LDS; per iter:
//   phase1: ds_read B frags + low-half A frags, MFMA cluster 1
//   phase2: ds_read high-half A frags, lgkmcnt(0), s_barrier (buffer free),
//           issue stage(t+2) into the just-freed buffer, MFMA cluster 2,
//           vmcnt(8) [t+1 landed, t+2 stays in flight], s_barrier
// LDS layout: row-major [BM][64] with 16B-granule XOR swizzle
//   physical_slot = logical_slot ^ (row & 7)    (both-sides: rule 21)
// ---------------------------------------------------------------------------
template <int BM, int BN, int WM, int WN, typename TC>
__global__ __launch_bounds__(WM*WN*64, 2) void gemm_pipe(
    const u16* __restrict__ A, const u16* __restrict__ B, TC* __restrict__ C,
    int K, int lda, int ldb, int ldc,
    long sA, long sB, long sC, float alpha,
    int gx, int gy, int q, int r)
{
    constexpr int NT   = WM * WN * 64;
    constexpr int MREP = BM / (WM * 16);
    constexpr int NREP = BN / (WN * 16);
    constexpr int MH   = MREP / 2;
    constexpr int CHA  = BM * 8 / NT;   // gload_lds per thread for A tile
    constexpr int CHB  = BN * 8 / NT;

    __shared__ u16 As[2][BM * 64];
    __shared__ u16 Bs[2][BN * 64];

    // T1: bijective XCD swizzle (m204)
    const int orig = blockIdx.x;
    const int xcd  = orig & 7, lo = orig >> 3;
    const int swz  = (xcd < r ? xcd * (q + 1) : r * (q + 1) + (xcd - r) * q) + lo;
    const int bx   = swz % gx;
    const int tmp2 = swz / gx;
    const int by   = tmp2 % gy;
    const int bz   = tmp2 / gy;

    const u16* Ab = A + (long)bz * sA + (long)by * BM * lda;
    const u16* Bb = B + (long)bz * sB + (long)bx * BN * ldb;

    const int tid = threadIdx.x;
    const int l   = tid & 63;
    const int wid = tid >> 6;
    const int wr  = (wid / WN) * (MREP * 16);
    const int wc  = (wid % WN) * (NREP * 16);
    const int lr  = l & 15;
    const int shi = l >> 4;             // 16B k-slot within 32-k-slice

    // stage one K-tile pair (A+B) into buffer `buf` — linear LDS dest,
    // inverse-swizzled global source
    auto stage = [&](int buf, int k0) {
#pragma unroll
        for (int i = 0; i < CHA; ++i) {
            const int c = tid + i * NT, row = c >> 3, p = c & 7;
            gload_lds16(Ab + (long)row * lda + k0 + ((p ^ (row & 7)) << 3),
                        &As[buf][c << 3]);
        }
#pragma unroll
        for (int i = 0; i < CHB; ++i) {
            const int c = tid + i * NT, row = c >> 3, p = c & 7;
            gload_lds16(Bb + (long)row * ldb + k0 + ((p ^ (row & 7)) << 3),
                        &Bs[buf][c << 3]);
        }
    };
    auto rdA = [&](int buf, int m, int ks) -> bf16x8 {
        const int row = wr + m * 16 + lr, slot = ks * 4 + shi;
        return *(const bf16x8*)&As[buf][row * 64 + ((slot ^ (row & 7)) << 3)];
    };
    auto rdB = [&](int buf, int n, int ks) -> bf16x8 {
        const int row = wc + n * 16 + lr, slot = ks * 4 + shi;
        return *(const bf16x8*)&Bs[buf][row * 64 + ((slot ^ (row & 7)) << 3)];
    };

    f32x4 acc[MREP][NREP] = {};
    const int nk = K / 64;

    // prologue: two tiles in flight
    stage(0, 0);
    stage(1, 64);
    asm volatile("s_waitcnt vmcnt(8)" ::: "memory");   // tile 0 landed
    __builtin_amdgcn_sched_barrier(0);
    __builtin_amdgcn_s_barrier();

    int cur = 0;
    for (int t = 0; t < nk; ++t) {
        bf16x8 bfr[NREP][2];
#pragma unroll
        for (int n = 0; n < NREP; ++n) {
            bfr[n][0] = rdB(cur, n, 0);
            bfr[n][1] = rdB(cur, n, 1);
        }
        bf16x8 af[MH][2];
#pragma unroll
        for (int m = 0; m < MH; ++m) {
            af[m][0] = rdA(cur, m, 0);
            af[m][1] = rdA(cur, m, 1);
        }
        __builtin_amdgcn_s_setprio(1);
#pragma unroll
        for (int m = 0; m < MH; ++m)
#pragma unroll
            for (int n = 0; n < NREP; ++n) {
                acc[m][n] = __builtin_amdgcn_mfma_f32_16x16x32_bf16(
                    af[m][0], bfr[n][0], acc[m][n], 0, 0, 0);
                acc[m][n] = __builtin_amdgcn_mfma_f32_16x16x32_bf16(
                    af[m][1], bfr[n][1], acc[m][n], 0, 0, 0);
            }
        __builtin_amdgcn_s_setprio(0);

        // phase 2: high-half A frags
        bf16x8 ah[MH][2];
#pragma unroll
        for (int m = 0; m < MH; ++m) {
            ah[m][0] = rdA(cur, MH + m, 0);
            ah[m][1] = rdA(cur, MH + m, 1);
        }
        asm volatile("s_waitcnt lgkmcnt(0)" ::: "memory");  // all reads of cur done
        __builtin_amdgcn_sched_barrier(0);
        __builtin_amdgcn_s_barrier();                       // buffer `cur` free
        if (t + 2 < nk) stage(cur, (t + 2) * 64);           // refill in flight
        __builtin_amdgcn_s_setprio(1);
#pragma unroll
        for (int m = 0; m < MH; ++m)
#pragma unroll
            for (int n = 0; n < NREP; ++n) {
                acc[MH + m][n] = __builtin_amdgcn_mfma_f32_16x16x32_bf16(
                    ah[m][0], bfr[n][0], acc[MH + m][n], 0, 0, 0);
                acc[MH + m][n] = __builtin_amdgcn_mfma_f32_16x16x32_bf16(
                    ah[m][1], bfr[n][1], acc[MH + m][n], 0, 0, 0);
            }
        __builtin_amdgcn_s_setprio(0);
        if (t + 2 < nk) {
            asm volatile("s_waitcnt vmcnt(8)" ::: "memory"); // t+1 landed
        } else {
            asm volatile("s_waitcnt vmcnt(0)" ::: "memory"); // tail: drain
        }
        __builtin_amdgcn_sched_barrier(0);
        __builtin_amdgcn_s_barrier();                        // next buffer ready
        cur ^= 1;
    }

    // epilogue: D mapping col = l&15, row = (l>>4)*4 + j
    TC*        Cb = C + (long)bz * sC;
    const long rB = (long)by * BM + wr + (l >> 4) * 4;
    const long cB = (long)bx * BN + wc + lr;
#pragma unroll
    for (int m = 0; m < MREP; ++m)
#pragma unroll
        for (int n = 0; n < NREP; ++n)
#pragma unroll
            for (int j = 0; j < 4; ++j)
                store_c(&Cb[(rB + m * 16 + j) * ldc + cB + n * 16],
                        acc[m][n][j] * alpha);
}

template <int BM, int BN, int WM, int WN, typename TC>
static inline void run_gemm(hipStream_t s, const u16* A, const u16* B, TC* C,
                            int M, int N, int K, int lda, int ldb, int ldc,
                            long sA, long sB, long sC, float alpha, int batch)
{
    const int gx = N / BN, gy = M / BM;
    const int nwg = gx * gy * batch;
    gemm_pipe<BM, BN, WM, WN, TC><<<nwg, WM * WN * 64, 0, s>>>(
        A, B, C, K, lda, ldb, ldc, sA, sB, sC, alpha, gx, gy, nwg / 8, nwg % 8);
}

// ---------------------------------------------------------------------------
// f32 -> bf16 convert, 4 elems/thread
// ---------------------------------------------------------------------------
__global__ __launch_bounds__(256) void cvt_f32_bf16(
    const float* __restrict__ in, u16* __restrict__ out, long n)
{
    long i = ((long)blockIdx.x * 256 + threadIdx.x) * 4;
    if (i >= n) return;
    float4 v = *(const float4*)(in + i);
    u16x4 w = { f2bf(v.x), f2bf(v.y), f2bf(v.z), f2bf(v.w) };
    *(u16x4*)(out + i) = w;
}

// all 4 weight matrices in one launch; dst regions contiguous in ws
__global__ __launch_bounds__(256) void cvt_w4(
    const float* __restrict__ w0, const float* __restrict__ w1,
    const float* __restrict__ w2, const float* __restrict__ w3,
    u16* __restrict__ out)
{
    const float* src = (blockIdx.y == 0) ? w0 : (blockIdx.y == 1) ? w1
                     : (blockIdx.y == 2) ? w2 : w3;
    long i = ((long)blockIdx.x * 256 + threadIdx.x) * 4;
    float4 v = *(const float4*)(src + i);
    u16x4 w = { f2bf(v.x), f2bf(v.y), f2bf(v.z), f2bf(v.w) };
    *(u16x4*)(out + (long)blockIdx.y * 1048576 + i) = w;
}

// ---------------------------------------------------------------------------
// V combine (logic gates on triplet projections) + transpose to Vt[b][o][t]
// ---------------------------------------------------------------------------
__global__ __launch_bounds__(256) void combine_v(
    const u16* __restrict__ vp, const int* __restrict__ ids,
    u16* __restrict__ Vt)
{
    __shared__ u16 tile[64][68];
    const int b  = blockIdx.z;
    const int t0 = blockIdx.x * 64;
    const int o0 = blockIdx.y * 64;
    const int tx = threadIdx.x;
    const int ty = threadIdx.y;

#pragma unroll
    for (int i = 0; i < 4; ++i) {
        const int  tloc = ty + i * 16;
        const int  t    = t0 + tloc;
        const long base = ((long)(b * 512 + t) * 3) * 1024 + o0 + tx * 4;
        const int  rel  = ids[(b * 512 + t) * 3];
        u16x4 r0 = *(const u16x4*)(vp + base);
        u16x4 r1 = *(const u16x4*)(vp + base + 1024);
        u16x4 r2 = *(const u16x4*)(vp + base + 2048);
#pragma unroll
        for (int c = 0; c < 4; ++c) {
            float vr = bf2f(r0[c]);
            float x1 = bf2f(r1[c]);
            float x2 = bf2f(r2[c]);
            float vf;
            switch (rel) {
                case 0:  vf = fminf(x1, x2);  break;
                case 1:  vf = fmaxf(x1, x2);  break;
                case 2:  vf = -x1;            break;
                case 3:  vf = fmaxf(-x1, x2); break;
                case 4:  vf = fabsf(x1 - x2); break;
                default: vf = vr;             break;
            }
            tile[tloc][tx * 4 + c] = f2bf(vf);
        }
    }
    __syncthreads();
#pragma unroll
    for (int j = 0; j < 4; ++j) {
        const int ol = ty + j * 16;
        u16x4 w;
#pragma unroll
        for (int c = 0; c < 4; ++c) w[c] = tile[tx * 4 + c][ol];
        *(u16x4*)(Vt + ((long)(b * 1024 + o0 + ol)) * 512 + t0 + tx * 4) = w;
    }
}

// ---------------------------------------------------------------------------
// Row softmax over 512 f32 scores -> bf16 probs. One wave per row.
// ---------------------------------------------------------------------------
__global__ __launch_bounds__(256) void softmax_rows(
    const float* __restrict__ S, u16* __restrict__ P)
{
    const int row = blockIdx.x * 4 + (threadIdx.x >> 6);
    const int l   = threadIdx.x & 63;
    const float4* src = (const float4*)(S + (long)row * 512);
    float4 a = src[l];
    float4 b = src[64 + l];

    float m = fmaxf(fmaxf(fmaxf(a.x, a.y), fmaxf(a.z, a.w)),
                    fmaxf(fmaxf(b.x, b.y), fmaxf(b.z, b.w)));
#pragma unroll
    for (int off = 32; off; off >>= 1) m = fmaxf(m, __shfl_xor(m, off));

    a.x = __expf(a.x - m); a.y = __expf(a.y - m);
    a.z = __expf(a.z - m); a.w = __expf(a.w - m);
    b.x = __expf(b.x - m); b.y = __expf(b.y - m);
    b.z = __expf(b.z - m); b.w = __expf(b.w - m);

    float s = a.x + a.y + a.z + a.w + b.x + b.y + b.z + b.w;
#pragma unroll
    for (int off = 32; off; off >>= 1) s += __shfl_xor(s, off);
    const float inv = 1.0f / s;

    u16x4 w0 = { f2bf(a.x * inv), f2bf(a.y * inv), f2bf(a.z * inv), f2bf(a.w * inv) };
    u16x4 w1 = { f2bf(b.x * inv), f2bf(b.y * inv), f2bf(b.z * inv), f2bf(b.w * inv) };
    u16x4* dst = (u16x4*)(P + (long)row * 512);
    dst[l]      = w0;
    dst[64 + l] = w1;
}

// ---------------------------------------------------------------------------
extern "C" void kernel_launch(void* const* d_in, const int* in_sizes, int n_in,
                              void* d_out, int out_size, void* d_ws, size_t ws_size,
                              hipStream_t stream)
{
    const float* hidden  = (const float*)d_in[0];
    const float* advisor = (const float*)d_in[1];
    const int*   ids     = (const int*)d_in[2];
    const float* Wq      = (const float*)d_in[3];
    const float* Wk      = (const float*)d_in[4];
    const float* Wv      = (const float*)d_in[5];
    const float* Wo      = (const float*)d_in[6];
    float*       out     = (float*)d_out;

    char* ws = (char*)d_ws;
    const long MB = 1L << 20;
    u16*   Wq_bf  = (u16*)(ws + 0 * MB);     // 2MB (Wk/Wv/Wo follow contiguously)
    u16*   Hbf    = (u16*)(ws + 8 * MB);     // 32MB  (dead after Q gemm)
    float* scores = (float*)(ws + 8 * MB);   // 32MB  (reuses Hbf)
    u16*   Abf    = (u16*)(ws + 40 * MB);    // 24MB  (dead after K/V gemms)
    u16*   P      = (u16*)(ws + 40 * MB);    // 16MB  (reuses Abf)
    u16*   Qbf    = (u16*)(ws + 64 * MB);    // 32MB  (dead after scores)
    u16*   ctx    = (u16*)(ws + 64 * MB);    // 32MB  (reuses Qbf)
    u16*   Kf     = (u16*)(ws + 96 * MB);    // 8MB
    u16*   Vt     = (u16*)(ws + 104 * MB);   // 8MB
    u16*   vp     = (u16*)(ws + 112 * MB);   // 24MB

    u16* Wk_bf = Wq_bf + 1048576;
    u16* Wv_bf = Wq_bf + 2097152;
    u16* Wo_bf = Wq_bf + 3145728;

    // 1) converts
    cvt_f32_bf16<<<16384, 256, 0, stream>>>(hidden,  Hbf, 16777216L);
    cvt_f32_bf16<<<12288, 256, 0, stream>>>(advisor, Abf, 12582912L);
    cvt_w4<<<dim3(1024, 4), 256, 0, stream>>>(Wq, Wk, Wv, Wo, Wq_bf);

    // 2) projections
    // Q = hidden @ Wq^T (16384 x 1024 x 1024)
    run_gemm<256, 256, 2, 4, u16>(stream, Hbf, Wq_bf, Qbf,
        16384, 1024, 1024, 1024, 1024, 1024, 0, 0, 0, 1.0f, 1);
    // K = trip0 @ Wk^T (4096 x 1024 x 1024), A row stride 3072
    run_gemm<128, 128, 2, 2, u16>(stream, Abf, Wk_bf, Kf,
        4096, 1024, 1024, 3072, 1024, 1024, 0, 0, 0, 1.0f, 1);
    // Vproj = advisor @ Wv^T (12288 x 1024 x 1024)
    run_gemm<256, 256, 2, 4, u16>(stream, Abf, Wv_bf, vp,
        12288, 1024, 1024, 1024, 1024, 1024, 0, 0, 0, 1.0f, 1);

    // 3) logic-gate combine + transpose -> Vt[b][o][t]
    combine_v<<<dim3(8, 16, 8), dim3(16, 16), 0, stream>>>(vp, ids, Vt);

    // 4) scores = Q @ K^T / 32  (batched 2048 x 512 x 1024), f32
    run_gemm<128, 128, 2, 2, float>(stream, Qbf, Kf, scores,
        2048, 512, 1024, 1024, 1024, 512,
        2048L * 1024, 512L * 1024, 2048L * 512, 0.03125f, 8);

    // 5) softmax rows -> P bf16
    softmax_rows<<<4096, 256, 0, stream>>>(scores, P);

    // 6) ctx = P @ Vt^T (batched 2048 x 1024 x 512)
    run_gemm<128, 128, 2, 2, u16>(stream, P, Vt, ctx,
        2048, 1024, 512, 512, 512, 1024,
        2048L * 512, 1024L * 512, 2048L * 1024, 1.0f, 8);

    // 7) out = ctx @ Wo^T (16384 x 1024 x 1024) -> f32
    run_gemm<256, 256, 2, 4, float>(stream, ctx, Wo_bf, out,
        16384, 1024, 1024, 1024, 1024, 1024, 0, 0, 0, 1.0f, 1);
}